// Round 7
// baseline (15908.496 us; speedup 1.0000x reference)
//
#include <hip/hip_runtime.h>
#include <math.h>

#define NN 256
#define BB 1024
#define NMAT 1025   // 1024 batch matrices + 1 for L0

typedef float f32x32 __attribute__((ext_vector_type(32)));

// Static device storage (rewritten every launch)
__device__ float g_T[4][NN*NN];      // T[c][j*256+i] = Ws(i,j)*E(i,j,a,b)/(V[i][a]V[j][b]), c=2a+b
__device__ float g_Ws[NN*NN];        // Ws[j*256+i] (symmetric)
__device__ float g_V[NN][2];
__device__ float g_ld[NMAT];

__device__ __forceinline__ float sigmf(float v) { return 1.0f / (1.0f + expf(-v)); }

__global__ void k_prep_v(const float* __restrict__ Vc) {
  int i = threadIdx.x;
  float a = sigmf(Vc[2*i]);
  float b = sigmf(Vc[2*i+1]);
  float s = a + b;
  g_V[i][0] = a / s;
  g_V[i][1] = b / s;
}

__global__ void k_prep_T(const float* __restrict__ W, const float* __restrict__ lam) {
  int j = blockIdx.x;
  int i = threadIdx.x;
  float vi0 = g_V[i][0], vi1 = g_V[i][1];
  float vj0 = g_V[j][0], vj1 = g_V[j][1];
  float ws;
  if (i > j)      ws = sigmf(W[i*NN + j]);
  else if (i < j) ws = sigmf(W[j*NN + i]);
  else            ws = 0.0f;
  g_Ws[j*NN + i] = ws;
  float s = sigmf(lam[i*NN + j]);
  float pi = vi0, pj = vj0;
  float lower = fmaxf(1e-7f, pi + pj - 1.0f);
  float upper = fminf(pi, pj);
  float P00 = lower + s * (upper - lower);
  float P01 = pi - P00;
  float P10 = pj - P00;
  float P11 = 1.0f - pi - pj + P00;
  if (i == j) { P00 = P01 = P10 = P11 = 0.0f; }
  P00 = fminf(fmaxf(P00, 0.0f), 1.0f);
  P01 = fminf(fmaxf(P01, 0.0f), 1.0f);
  P10 = fminf(fmaxf(P10, 0.0f), 1.0f);
  P11 = fminf(fmaxf(P11, 0.0f), 1.0f);
  int o = j*NN + i;
  g_T[0][o] = ws * P00 / (vi0 * vj0);
  g_T[1][o] = ws * P01 / (vi0 * vj1);
  g_T[2][o] = ws * P10 / (vi1 * vj0);
  g_T[3][o] = ws * P11 / (vi1 * vj1);
}

// ---------- macro helpers (all vector element indices are literals) ----------

// swizzled float-index of chunk c within group g (chunk = 4 floats, 16B)
#define UIDX(g_, c_) (((g_) << 5) + ((((c_) ^ (g_)) & 7) << 2))

// build one column (literal cc); batch path
#define BCOLT(cc) { \
  const int gcn = ((G << 5) + (cc) + 1) & 255; \
  const int off = xs[gcn]*(NN*NN) + (gcn << 8); \
  float w0 = b0[off], w1 = b1[off], w2 = b2[off], w3 = b3[off]; \
  if (((cc) == 31) && (G == 7)) { w0 = 0; w1 = 0; w2 = 0; w3 = 0; } \
  s0 += w0; s1 += w1; s2 += w2; s3 += w3; \
  v0[(cc)] = -w0; v1[(cc)] = -w1; v2[(cc)] = -w2; v3[(cc)] = -w3; }

// build one column (literal cc); L0 path
#define BCOLW(cc) { \
  const int gcn = ((G << 5) + (cc) + 1) & 255; \
  const int off = (gcn << 8); \
  float w0 = b0[off], w1 = b1[off], w2 = b2[off], w3 = b3[off]; \
  if (((cc) == 31) && (G == 7)) { w0 = 0; w1 = 0; w2 = 0; w3 = 0; } \
  s0 += w0; s1 += w1; s2 += w2; s3 += w3; \
  v0[(cc)] = -w0; v1[(cc)] = -w1; v2[(cc)] = -w2; v3[(cc)] = -w3; }

#define B4(M,c)  M(c) M((c)+1) M((c)+2) M((c)+3)
#define B16(M,c) B4(M,c) B4(M,(c)+4) B4(M,(c)+8) B4(M,(c)+12)
#define B32(M)   B16(M,0) B16(M,16)

// store vector vv as the u-row for step (K)+1 (buffer ((K)+1)&1), swizzled
#define STOREU_V(vv, K) { _Pragma("unroll") \
  for (int c_ = 0; c_ < 8; ++c_) { \
    *(float4*)&urow_f[((((K)+1) & 1) << 8) + UIDX(G, c_)] = \
      make_float4(vv[4*c_], vv[4*c_+1], vv[4*c_+2], vv[4*c_+3]); } }

#define STOREU(K) { \
  if      (((((K)+1)) & 3) == 0) { STOREU_V(v0, K) } \
  else if (((((K)+1)) & 3) == 1) { STOREU_V(v1, K) } \
  else if (((((K)+1)) & 3) == 2) { STOREU_V(v2, K) } \
  else                           { STOREU_V(v3, K) } }

#define PIVV(KP) ( (((KP) & 3) == 0) ? v0[(KP) & 31] : \
                   (((KP) & 3) == 1) ? v1[(KP) & 31] : \
                   (((KP) & 3) == 2) ? v2[(KP) & 31] : v3[(KP) & 31] )

// one elimination step, K literal
#define STEP(K) { \
  __syncthreads(); \
  if (4*R + 3 > (K)) { \
    const float ukk = urow_f[(((K) & 1) << 8) + UIDX(((K) >> 5), (((K) >> 2) & 7)) + ((K) & 3)]; \
    const float rk = __builtin_amdgcn_rcpf(ukk); \
    const float4 ca = colbuf[(K) & 1][R]; \
    const float m0 = ca.x*rk, m1 = ca.y*rk, m2 = ca.z*rk, m3 = ca.w*rk; \
    if ((G << 5) + 31 > (K)) { \
      f32x32 uu; \
      _Pragma("unroll") \
      for (int c_ = 0; c_ < 8; ++c_) { \
        float4 u4 = *(const float4*)&urow_f[(((K) & 1) << 8) + UIDX(G, c_)]; \
        uu[4*c_] = u4.x; uu[4*c_+1] = u4.y; uu[4*c_+2] = u4.z; uu[4*c_+3] = u4.w; \
      } \
      v0 -= m0*uu; v1 -= m1*uu; v2 -= m2*uu; v3 -= m3*uu; \
      if (R == (((K)+1) >> 2)) { STOREU(K) } \
      if (G == (((K)+1) >> 5)) { \
        colbuf[((K)+1) & 1][R] = make_float4(v0[((K)+1) & 31], v1[((K)+1) & 31], \
                                             v2[((K)+1) & 31], v3[((K)+1) & 31]); \
        if (R == (((K)+1) >> 2)) pivbuf[(K)+1] = PIVV((K)+1); \
      } \
    } \
  } \
}

#define S2(K)   STEP(K) STEP((K)+1)
#define S4(K)   S2(K)  S2((K)+2)
#define S8(K)   S4(K)  S4((K)+4)
#define S16(K)  S8(K)  S8((K)+8)
#define S32(K)  S16(K) S16((K)+16)
#define S64(K)  S32(K) S32((K)+32)
#define S128(K) S64(K) S64((K)+64)

// One workgroup (512 thr) per matrix. Thread (R = t>>3, G = t&7) owns rows
// 4R..4R+3, cols 32G..32G+31, in 4 named f32x32 SSA vectors (128 VGPRs data).
// Right-looking no-pivot LU; one barrier/step; colbuf (pivot column) and
// urow (pivot row, XOR-bank-swizzled) double-buffered in LDS.
// launch_bounds(512,4): 4 waves/EU = 16 waves/CU = 2 blocks/CU -> barrier
// stalls of one block overlap the other block's VALU work. VGPR cap = 128.
__global__ __launch_bounds__(512, 4) void k_lu(const int* __restrict__ x) {
  __shared__ __align__(16) float urow_f[2*NN];
  __shared__ float4 colbuf[2][64];
  __shared__ float  pivbuf[NN];
  __shared__ float  rowsum[NN];
  __shared__ float  psum[8][NN];
  __shared__ int    xs[NN];
  __shared__ float  red[4];

  const int t = threadIdx.x;
  const int R = t >> 3;   // row-group: rows 4R..4R+3
  const int G = t & 7;    // col-group: cols 32G..32G+31
  // L0 (matrix BB) runs as block 0 so it isn't a lone straggler at the end
  const int m = (blockIdx.x == 0) ? BB : (blockIdx.x - 1);

  if (m < BB && t < NN) xs[t] = x[m*NN + t];
  __syncthreads();

  f32x32 v0, v1, v2, v3;
  float s0 = 0, s1 = 0, s2 = 0, s3 = 0;

  // ---- build: gather 4x32 block; accumulate per-row partial sums ----
  {
    const int r0i = (4*R + 1) & 255, r1i = (4*R + 2) & 255;
    const int r2i = (4*R + 3) & 255, r3i = (4*R + 4) & 255;
    if (m < BB) {
      const float* Tb = &g_T[0][0];
      const float* b0 = Tb + 2*xs[r0i]*(NN*NN) + r0i;
      const float* b1 = Tb + 2*xs[r1i]*(NN*NN) + r1i;
      const float* b2 = Tb + 2*xs[r2i]*(NN*NN) + r2i;
      const float* b3 = Tb + 2*xs[r3i]*(NN*NN) + r3i;
      B32(BCOLT)
    } else {
      const float* b0 = g_Ws + r0i; const float* b1 = g_Ws + r1i;
      const float* b2 = g_Ws + r2i; const float* b3 = g_Ws + r3i;
      B32(BCOLW)
    }
  }
  *(float4*)&psum[G][4*R] = make_float4(s0, s1, s2, s3);
  __syncthreads();

  // ---- per-row total: sum 8 partials + original-col-0 term ----
  if (t < NN) {
    const int r = t;
    const int ri = (r + 1) & 255;
    float tot = psum[0][r] + psum[1][r] + psum[2][r] + psum[3][r]
              + psum[4][r] + psum[5][r] + psum[6][r] + psum[7][r];
    float w0;
    if (m < BB) w0 = g_T[0][(2*xs[ri] + xs[0])*(NN*NN) + ri];
    else        w0 = g_Ws[ri];
    rowsum[r] = tot + w0;
  }
  __syncthreads();

  // ---- insert diagonal (literal element positions per R&7 arm) ----
  if (G == (R >> 3)) {
    float4 ra = *(const float4*)&rowsum[4*R];
    switch (R & 7) {
      case 0: v0[0]  = ra.x; v1[1]  = ra.y; v2[2]  = ra.z; v3[3]  = ra.w; break;
      case 1: v0[4]  = ra.x; v1[5]  = ra.y; v2[6]  = ra.z; v3[7]  = ra.w; break;
      case 2: v0[8]  = ra.x; v1[9]  = ra.y; v2[10] = ra.z; v3[11] = ra.w; break;
      case 3: v0[12] = ra.x; v1[13] = ra.y; v2[14] = ra.z; v3[15] = ra.w; break;
      case 4: v0[16] = ra.x; v1[17] = ra.y; v2[18] = ra.z; v3[19] = ra.w; break;
      case 5: v0[20] = ra.x; v1[21] = ra.y; v2[22] = ra.z; v3[23] = ra.w; break;
      case 6: v0[24] = ra.x; v1[25] = ra.y; v2[26] = ra.z; v3[27] = ra.w; break;
      default:v0[28] = ra.x; v1[29] = ra.y; v2[30] = ra.z; v3[31] = ra.w; break;
    }
  }
  // pad row 255 = e_255
  if (R == 63) {
    v3 = (f32x32)(0.0f);
    if (G == 7) v3[31] = 1.0f;
  }
  // initial broadcasts into buffer 0 (K = -1 gives buffer ((K)+1)&1 = 0)
  if (R == 0) { STOREU_V(v0, -1) }
  if (G == 0) colbuf[0][R] = make_float4(v0[0], v1[0], v2[0], v3[0]);
  if (t == 0) pivbuf[0] = v0[0];

  // ---- 255 elimination steps ----
  S128(0) S64(128) S32(192) S16(224) S8(240) S4(248) S2(252) STEP(254)

  // ---- log|det| = sum log|u_kk| ----
  __syncthreads();
  if (t < NN) {
    float lg = logf(fabsf(pivbuf[t]));
    #pragma unroll
    for (int off = 32; off > 0; off >>= 1) lg += __shfl_down(lg, off, 64);
    if ((t & 63) == 0) red[t >> 6] = lg;
  }
  __syncthreads();
  if (t == 0) g_ld[m] = red[0] + red[1] + red[2] + red[3];
}

__global__ void k_final(const int* __restrict__ x, float* __restrict__ out) {
  __shared__ float red[4];
  int b = blockIdx.x, t = threadIdx.x;
  int xv = x[b*NN + t];
  float lg = logf(g_V[t][xv]);
  #pragma unroll
  for (int off = 32; off > 0; off >>= 1) lg += __shfl_down(lg, off, 64);
  if ((t & 63) == 0) red[t >> 6] = lg;
  __syncthreads();
  if (t == 0) out[b] = (red[0] + red[1] + red[2] + red[3]) + g_ld[b] - g_ld[BB];
}

extern "C" void kernel_launch(void* const* d_in, const int* in_sizes, int n_in,
                              void* d_out, int out_size, void* d_ws, size_t ws_size,
                              hipStream_t stream) {
  const float* W   = (const float*)d_in[0];
  const float* lam = (const float*)d_in[1];
  const float* Vc  = (const float*)d_in[2];
  const int*   x   = (const int*)d_in[3];
  float* out = (float*)d_out;

  k_prep_v<<<dim3(1),    dim3(NN), 0, stream>>>(Vc);
  k_prep_T<<<dim3(NN),   dim3(NN), 0, stream>>>(W, lam);
  k_lu    <<<dim3(NMAT), dim3(512), 0, stream>>>(x);
  k_final <<<dim3(BB),   dim3(NN), 0, stream>>>(x, out);
}

// Round 8
// 1021.565 us; speedup vs baseline: 15.5727x; 15.5727x over previous
//
#include <hip/hip_runtime.h>
#include <math.h>

#define NN 256
#define BB 1024
#define NMAT 1025   // 1024 batch matrices + 1 for L0

typedef float f32x32 __attribute__((ext_vector_type(32)));

// Static device storage (rewritten every launch)
__device__ float g_T[4][NN*NN];      // T[c][j*256+i] = Ws(i,j)*E(i,j,a,b)/(V[i][a]V[j][b]), c=2a+b
__device__ float g_Ws[NN*NN];        // Ws[j*256+i] (symmetric)
__device__ float g_V[NN][2];
__device__ float g_ld[NMAT];

__device__ __forceinline__ float sigmf(float v) { return 1.0f / (1.0f + expf(-v)); }

__global__ void k_prep_v(const float* __restrict__ Vc) {
  int i = threadIdx.x;
  float a = sigmf(Vc[2*i]);
  float b = sigmf(Vc[2*i+1]);
  float s = a + b;
  g_V[i][0] = a / s;
  g_V[i][1] = b / s;
}

__global__ void k_prep_T(const float* __restrict__ W, const float* __restrict__ lam) {
  int j = blockIdx.x;
  int i = threadIdx.x;
  float vi0 = g_V[i][0], vi1 = g_V[i][1];
  float vj0 = g_V[j][0], vj1 = g_V[j][1];
  float ws;
  if (i > j)      ws = sigmf(W[i*NN + j]);
  else if (i < j) ws = sigmf(W[j*NN + i]);
  else            ws = 0.0f;
  g_Ws[j*NN + i] = ws;
  float s = sigmf(lam[i*NN + j]);
  float pi = vi0, pj = vj0;
  float lower = fmaxf(1e-7f, pi + pj - 1.0f);
  float upper = fminf(pi, pj);
  float P00 = lower + s * (upper - lower);
  float P01 = pi - P00;
  float P10 = pj - P00;
  float P11 = 1.0f - pi - pj + P00;
  if (i == j) { P00 = P01 = P10 = P11 = 0.0f; }
  P00 = fminf(fmaxf(P00, 0.0f), 1.0f);
  P01 = fminf(fmaxf(P01, 0.0f), 1.0f);
  P10 = fminf(fmaxf(P10, 0.0f), 1.0f);
  P11 = fminf(fmaxf(P11, 0.0f), 1.0f);
  int o = j*NN + i;
  g_T[0][o] = ws * P00 / (vi0 * vj0);
  g_T[1][o] = ws * P01 / (vi0 * vj1);
  g_T[2][o] = ws * P10 / (vi1 * vj0);
  g_T[3][o] = ws * P11 / (vi1 * vj1);
}

// ---------- macro helpers (all vector element indices are literals) ----------

// swizzled float-index of chunk c within group g (chunk = 4 floats, 16B)
#define UIDX(g_, c_) (((g_) << 5) + ((((c_) ^ (g_)) & 7) << 2))

// build one column (literal cc); batch path
#define BCOLT(cc) { \
  const int gcn = ((G << 5) + (cc) + 1) & 255; \
  const int off = xs[gcn]*(NN*NN) + (gcn << 8); \
  float w0 = b0[off], w1 = b1[off], w2 = b2[off], w3 = b3[off]; \
  if (((cc) == 31) && (G == 7)) { w0 = 0; w1 = 0; w2 = 0; w3 = 0; } \
  s0 += w0; s1 += w1; s2 += w2; s3 += w3; \
  v0[(cc)] = -w0; v1[(cc)] = -w1; v2[(cc)] = -w2; v3[(cc)] = -w3; }

// build one column (literal cc); L0 path
#define BCOLW(cc) { \
  const int gcn = ((G << 5) + (cc) + 1) & 255; \
  const int off = (gcn << 8); \
  float w0 = b0[off], w1 = b1[off], w2 = b2[off], w3 = b3[off]; \
  if (((cc) == 31) && (G == 7)) { w0 = 0; w1 = 0; w2 = 0; w3 = 0; } \
  s0 += w0; s1 += w1; s2 += w2; s3 += w3; \
  v0[(cc)] = -w0; v1[(cc)] = -w1; v2[(cc)] = -w2; v3[(cc)] = -w3; }

#define B4(M,c)  M(c) M((c)+1) M((c)+2) M((c)+3)
#define B16(M,c) B4(M,c) B4(M,(c)+4) B4(M,(c)+8) B4(M,(c)+12)
#define B32(M)   B16(M,0) B16(M,16)

// store vector vv (this thread's 32-col slice of a row) into buffer dst, parity par
#define STROW(vv, dst, par) { _Pragma("unroll") \
  for (int c_ = 0; c_ < 8; ++c_) { \
    *(float4*)&dst[((par) << 8) + UIDX(G, c_)] = \
      make_float4(vv[4*c_], vv[4*c_+1], vv[4*c_+2], vv[4*c_+3]); } }

// select by literal row-in-thread index (ri)&3
#define STROW_SEL(ri, dst, par) { \
  if      (((ri) & 3) == 0) { STROW(v0, dst, par) } \
  else if (((ri) & 3) == 1) { STROW(v1, dst, par) } \
  else if (((ri) & 3) == 2) { STROW(v2, dst, par) } \
  else                      { STROW(v3, dst, par) } }

#define PIVV(KP) ( (((KP) & 3) == 0) ? v0[(KP) & 31] : \
                   (((KP) & 3) == 1) ? v1[(KP) & 31] : \
                   (((KP) & 3) == 2) ? v2[(KP) & 31] : v3[(KP) & 31] )

// ---- fused rank-2 elimination step: pivots K=2S and K+1, ONE barrier ----
// reads parity p=S&1 buffers; writes parity p^1 for the next fused step.
#define FSTEP(S) { \
  __syncthreads(); \
  { enum { K_ = 2*(S), p_ = (S)&1, q_ = ((S)&1)^1 }; \
  if (4*R + 3 > K_) { \
    const float uKK  = urA_f[(p_ << 8) + UIDX((K_) >> 5, ((K_) >> 2) & 7) + ((K_) & 3)]; \
    const float uK1  = urA_f[(p_ << 8) + UIDX((K_+1) >> 5, ((K_+1) >> 2) & 7) + ((K_+1) & 3)]; \
    const float uP11 = urB_f[(p_ << 8) + UIDX((K_+1) >> 5, ((K_+1) >> 2) & 7) + ((K_+1) & 3)]; \
    const float aK1K = ((const float*)colA)[(p_ << 8) + (K_+1)]; \
    const float rk  = __builtin_amdgcn_rcpf(uKK); \
    const float mK1 = aK1K * rk; \
    const float u11 = uP11 - mK1 * uK1; \
    const float rk2 = __builtin_amdgcn_rcpf(u11); \
    const float4 ca = colA[p_][R], cb = colB[p_][R]; \
    const float m0 = ca.x*rk, m1 = ca.y*rk, m2 = ca.z*rk, m3 = ca.w*rk; \
    const float n0 = (cb.x - m0*uK1)*rk2, n1 = (cb.y - m1*uK1)*rk2; \
    const float n2 = (cb.z - m2*uK1)*rk2, n3 = (cb.w - m3*uK1)*rk2; \
    if (R == ((K_+2) >> 2) && G == ((K_+2) >> 5)) pivbuf[K_+1] = u11; \
    if ((G << 5) + 31 > K_ + 1) { \
      _Pragma("unroll") \
      for (int c_ = 0; c_ < 8; ++c_) { \
        const float4 u4  = *(const float4*)&urA_f[(p_ << 8) + UIDX(G, c_)]; \
        const float4 uP4 = *(const float4*)&urB_f[(p_ << 8) + UIDX(G, c_)]; \
        const float w0 = uP4.x - mK1*u4.x, w1 = uP4.y - mK1*u4.y; \
        const float w2 = uP4.z - mK1*u4.z, w3 = uP4.w - mK1*u4.w; \
        v0[4*c_+0] = v0[4*c_+0] - m0*u4.x - n0*w0; \
        v0[4*c_+1] = v0[4*c_+1] - m0*u4.y - n0*w1; \
        v0[4*c_+2] = v0[4*c_+2] - m0*u4.z - n0*w2; \
        v0[4*c_+3] = v0[4*c_+3] - m0*u4.w - n0*w3; \
        v1[4*c_+0] = v1[4*c_+0] - m1*u4.x - n1*w0; \
        v1[4*c_+1] = v1[4*c_+1] - m1*u4.y - n1*w1; \
        v1[4*c_+2] = v1[4*c_+2] - m1*u4.z - n1*w2; \
        v1[4*c_+3] = v1[4*c_+3] - m1*u4.w - n1*w3; \
        v2[4*c_+0] = v2[4*c_+0] - m2*u4.x - n2*w0; \
        v2[4*c_+1] = v2[4*c_+1] - m2*u4.y - n2*w1; \
        v2[4*c_+2] = v2[4*c_+2] - m2*u4.z - n2*w2; \
        v2[4*c_+3] = v2[4*c_+3] - m2*u4.w - n2*w3; \
        v3[4*c_+0] = v3[4*c_+0] - m3*u4.x - n3*w0; \
        v3[4*c_+1] = v3[4*c_+1] - m3*u4.y - n3*w1; \
        v3[4*c_+2] = v3[4*c_+2] - m3*u4.z - n3*w2; \
        v3[4*c_+3] = v3[4*c_+3] - m3*u4.w - n3*w3; \
      } \
      if (R == ((K_+2) >> 2)) { STROW_SEL(K_+2, urA_f, q_) } \
      if (R == ((K_+3) >> 2)) { STROW_SEL(K_+3, urB_f, q_) } \
      if (G == ((K_+2) >> 5)) { \
        colA[q_][R] = make_float4(v0[(K_+2) & 31], v1[(K_+2) & 31], \
                                  v2[(K_+2) & 31], v3[(K_+2) & 31]); \
        colB[q_][R] = make_float4(v0[(K_+3) & 31], v1[(K_+3) & 31], \
                                  v2[(K_+3) & 31], v3[(K_+3) & 31]); \
        if (R == ((K_+2) >> 2)) pivbuf[K_+2] = PIVV(K_+2); \
      } \
    } \
  } } \
}

#define F2(S)  FSTEP(S) FSTEP((S)+1)
#define F4(S)  F2(S)  F2((S)+2)
#define F8(S)  F4(S)  F4((S)+4)
#define F16(S) F8(S)  F8((S)+8)
#define F32(S) F16(S) F16((S)+16)
#define F64(S) F32(S) F32((S)+32)

// One workgroup (512 thr) per matrix. Thread (R = t>>3, G = t&7) owns rows
// 4R..4R+3, cols 32G..32G+31, in 4 named f32x32 SSA vectors.
// Rank-2 right-looking no-pivot LU: 127 fused steps, ONE barrier each.
// Broadcasts (double-buffered, XOR-bank-swizzled rows): pivot row K (urA),
// pre-row K+1 (urB), col K (colA), pre-col K+1 (colB). Each thread
// reconstructs row K+1's update from broadcast scalars (rank-2 formula).
// launch_bounds(512,2): VGPR cap 256 — the config measured spill-free (R6).
__global__ __launch_bounds__(512, 2) void k_lu(const int* __restrict__ x) {
  __shared__ __align__(16) float urA_f[2*NN];
  __shared__ __align__(16) float urB_f[2*NN];
  __shared__ float4 colA[2][64];
  __shared__ float4 colB[2][64];
  __shared__ float  pivbuf[NN];
  __shared__ float  rowsum[NN];
  __shared__ float  psum[8][NN];
  __shared__ int    xs[NN];
  __shared__ float  red[4];

  const int t = threadIdx.x;
  const int R = t >> 3;   // row-group: rows 4R..4R+3
  const int G = t & 7;    // col-group: cols 32G..32G+31
  // L0 (matrix BB) runs as block 0 so it isn't a lone straggler at the end
  const int m = (blockIdx.x == 0) ? BB : (blockIdx.x - 1);

  if (m < BB && t < NN) xs[t] = x[m*NN + t];
  __syncthreads();

  f32x32 v0, v1, v2, v3;
  float s0 = 0, s1 = 0, s2 = 0, s3 = 0;

  // ---- build: gather 4x32 block; accumulate per-row partial sums ----
  {
    const int r0i = (4*R + 1) & 255, r1i = (4*R + 2) & 255;
    const int r2i = (4*R + 3) & 255, r3i = (4*R + 4) & 255;
    if (m < BB) {
      const float* Tb = &g_T[0][0];
      const float* b0 = Tb + 2*xs[r0i]*(NN*NN) + r0i;
      const float* b1 = Tb + 2*xs[r1i]*(NN*NN) + r1i;
      const float* b2 = Tb + 2*xs[r2i]*(NN*NN) + r2i;
      const float* b3 = Tb + 2*xs[r3i]*(NN*NN) + r3i;
      B32(BCOLT)
    } else {
      const float* b0 = g_Ws + r0i; const float* b1 = g_Ws + r1i;
      const float* b2 = g_Ws + r2i; const float* b3 = g_Ws + r3i;
      B32(BCOLW)
    }
  }
  *(float4*)&psum[G][4*R] = make_float4(s0, s1, s2, s3);
  __syncthreads();

  // ---- per-row total: sum 8 partials + original-col-0 term ----
  if (t < NN) {
    const int r = t;
    const int ri = (r + 1) & 255;
    float tot = psum[0][r] + psum[1][r] + psum[2][r] + psum[3][r]
              + psum[4][r] + psum[5][r] + psum[6][r] + psum[7][r];
    float w0;
    if (m < BB) w0 = g_T[0][(2*xs[ri] + xs[0])*(NN*NN) + ri];
    else        w0 = g_Ws[ri];
    rowsum[r] = tot + w0;
  }
  __syncthreads();

  // ---- insert diagonal (literal element positions per R&7 arm) ----
  if (G == (R >> 3)) {
    float4 ra = *(const float4*)&rowsum[4*R];
    switch (R & 7) {
      case 0: v0[0]  = ra.x; v1[1]  = ra.y; v2[2]  = ra.z; v3[3]  = ra.w; break;
      case 1: v0[4]  = ra.x; v1[5]  = ra.y; v2[6]  = ra.z; v3[7]  = ra.w; break;
      case 2: v0[8]  = ra.x; v1[9]  = ra.y; v2[10] = ra.z; v3[11] = ra.w; break;
      case 3: v0[12] = ra.x; v1[13] = ra.y; v2[14] = ra.z; v3[15] = ra.w; break;
      case 4: v0[16] = ra.x; v1[17] = ra.y; v2[18] = ra.z; v3[19] = ra.w; break;
      case 5: v0[20] = ra.x; v1[21] = ra.y; v2[22] = ra.z; v3[23] = ra.w; break;
      case 6: v0[24] = ra.x; v1[25] = ra.y; v2[26] = ra.z; v3[27] = ra.w; break;
      default:v0[28] = ra.x; v1[29] = ra.y; v2[30] = ra.z; v3[31] = ra.w; break;
    }
  }
  // pad row 255 = e_255; its pivot is 1 (row 255 never changes: its
  // multipliers are all 0), so pivbuf[255] is preset here.
  if (R == 63) {
    v3 = (f32x32)(0.0f);
    if (G == 7) { v3[31] = 1.0f; pivbuf[255] = 1.0f; }
  }
  // initial broadcasts into parity-0 buffers: row 0, pre-row 1, col 0, pre-col 1
  if (R == 0) { STROW(v0, urA_f, 0) STROW(v1, urB_f, 0) }
  if (G == 0) {
    colA[0][R] = make_float4(v0[0], v1[0], v2[0], v3[0]);
    colB[0][R] = make_float4(v0[1], v1[1], v2[1], v3[1]);
  }
  if (t == 0) pivbuf[0] = v0[0];

  // ---- 127 fused rank-2 steps: pivots 0..253. Step 254 is a no-op
  // (only updates pad row 255, whose multipliers are 0) and pivot 255 = 1.
  F64(0) F32(64) F16(96) F8(112) F4(120) F2(124) FSTEP(126)

  // ---- log|det| = sum log|u_kk| ----
  __syncthreads();
  if (t < NN) {
    float lg = logf(fabsf(pivbuf[t]));
    #pragma unroll
    for (int off = 32; off > 0; off >>= 1) lg += __shfl_down(lg, off, 64);
    if ((t & 63) == 0) red[t >> 6] = lg;
  }
  __syncthreads();
  if (t == 0) g_ld[m] = red[0] + red[1] + red[2] + red[3];
}

__global__ void k_final(const int* __restrict__ x, float* __restrict__ out) {
  __shared__ float red[4];
  int b = blockIdx.x, t = threadIdx.x;
  int xv = x[b*NN + t];
  float lg = logf(g_V[t][xv]);
  #pragma unroll
  for (int off = 32; off > 0; off >>= 1) lg += __shfl_down(lg, off, 64);
  if ((t & 63) == 0) red[t >> 6] = lg;
  __syncthreads();
  if (t == 0) out[b] = (red[0] + red[1] + red[2] + red[3]) + g_ld[b] - g_ld[BB];
}

extern "C" void kernel_launch(void* const* d_in, const int* in_sizes, int n_in,
                              void* d_out, int out_size, void* d_ws, size_t ws_size,
                              hipStream_t stream) {
  const float* W   = (const float*)d_in[0];
  const float* lam = (const float*)d_in[1];
  const float* Vc  = (const float*)d_in[2];
  const int*   x   = (const int*)d_in[3];
  float* out = (float*)d_out;

  k_prep_v<<<dim3(1),    dim3(NN), 0, stream>>>(Vc);
  k_prep_T<<<dim3(NN),   dim3(NN), 0, stream>>>(W, lam);
  k_lu    <<<dim3(NMAT), dim3(512), 0, stream>>>(x);
  k_final <<<dim3(BB),   dim3(NN), 0, stream>>>(x, out);
}

// Round 9
// 780.702 us; speedup vs baseline: 20.3772x; 1.3085x over previous
//
#include <hip/hip_runtime.h>
#include <math.h>

#define NN 256
#define BB 1024
#define NMAT 1025   // 1024 batch matrices + 1 for L0

typedef float f32x32 __attribute__((ext_vector_type(32)));

// Static device storage (rewritten every launch)
__device__ float g_T[4][NN*NN];      // T[c][j*256+i] = Ws(i,j)*E(i,j,a,b)/(V[i][a]V[j][b]), c=2a+b
__device__ float g_Ws[NN*NN];        // Ws[j*256+i] (symmetric)
__device__ float g_V[NN][2];
__device__ float g_ld[NMAT];

__device__ __forceinline__ float sigmf(float v) { return 1.0f / (1.0f + expf(-v)); }

// block-uniform value -> SGPR (kills per-lane VGPR copies of uniform scalars)
__device__ __forceinline__ float rfl(float x) {
  return __builtin_bit_cast(float, __builtin_amdgcn_readfirstlane(__builtin_bit_cast(int, x)));
}

__global__ void k_prep_v(const float* __restrict__ Vc) {
  int i = threadIdx.x;
  float a = sigmf(Vc[2*i]);
  float b = sigmf(Vc[2*i+1]);
  float s = a + b;
  g_V[i][0] = a / s;
  g_V[i][1] = b / s;
}

__global__ void k_prep_T(const float* __restrict__ W, const float* __restrict__ lam) {
  int j = blockIdx.x;
  int i = threadIdx.x;
  float vi0 = g_V[i][0], vi1 = g_V[i][1];
  float vj0 = g_V[j][0], vj1 = g_V[j][1];
  float ws;
  if (i > j)      ws = sigmf(W[i*NN + j]);
  else if (i < j) ws = sigmf(W[j*NN + i]);
  else            ws = 0.0f;
  g_Ws[j*NN + i] = ws;
  float s = sigmf(lam[i*NN + j]);
  float pi = vi0, pj = vj0;
  float lower = fmaxf(1e-7f, pi + pj - 1.0f);
  float upper = fminf(pi, pj);
  float P00 = lower + s * (upper - lower);
  float P01 = pi - P00;
  float P10 = pj - P00;
  float P11 = 1.0f - pi - pj + P00;
  if (i == j) { P00 = P01 = P10 = P11 = 0.0f; }
  P00 = fminf(fmaxf(P00, 0.0f), 1.0f);
  P01 = fminf(fmaxf(P01, 0.0f), 1.0f);
  P10 = fminf(fmaxf(P10, 0.0f), 1.0f);
  P11 = fminf(fmaxf(P11, 0.0f), 1.0f);
  int o = j*NN + i;
  g_T[0][o] = ws * P00 / (vi0 * vj0);
  g_T[1][o] = ws * P01 / (vi0 * vj1);
  g_T[2][o] = ws * P10 / (vi1 * vj0);
  g_T[3][o] = ws * P11 / (vi1 * vj1);
}

// ---------- macro helpers (all vector element indices are literals) ----------

// swizzled float-index of chunk c within group g (chunk = 4 floats, 16B)
#define UIDX(g_, c_) (((g_) << 5) + ((((c_) ^ (g_)) & 7) << 2))

// build one column (literal cc); batch path
#define BCOLT(cc) { \
  const int gcn = ((G << 5) + (cc) + 1) & 255; \
  const int off = xs[gcn]*(NN*NN) + (gcn << 8); \
  float w0 = b0[off], w1 = b1[off], w2 = b2[off], w3 = b3[off]; \
  if (((cc) == 31) && (G == 7)) { w0 = 0; w1 = 0; w2 = 0; w3 = 0; } \
  s0 += w0; s1 += w1; s2 += w2; s3 += w3; \
  v0[(cc)] = -w0; v1[(cc)] = -w1; v2[(cc)] = -w2; v3[(cc)] = -w3; }

// build one column (literal cc); L0 path
#define BCOLW(cc) { \
  const int gcn = ((G << 5) + (cc) + 1) & 255; \
  const int off = (gcn << 8); \
  float w0 = b0[off], w1 = b1[off], w2 = b2[off], w3 = b3[off]; \
  if (((cc) == 31) && (G == 7)) { w0 = 0; w1 = 0; w2 = 0; w3 = 0; } \
  s0 += w0; s1 += w1; s2 += w2; s3 += w3; \
  v0[(cc)] = -w0; v1[(cc)] = -w1; v2[(cc)] = -w2; v3[(cc)] = -w3; }

#define B4(M,c)  M(c) M((c)+1) M((c)+2) M((c)+3)
#define B16(M,c) B4(M,c) B4(M,(c)+4) B4(M,(c)+8) B4(M,(c)+12)
#define B32(M)   B16(M,0) B16(M,16)

// store vector vv (this thread's 32-col slice of a row) into buffer dst, parity par
#define STROW(vv, dst, par) { _Pragma("unroll") \
  for (int c_ = 0; c_ < 8; ++c_) { \
    *(float4*)&dst[((par) << 8) + UIDX(G, c_)] = \
      make_float4(vv[4*c_], vv[4*c_+1], vv[4*c_+2], vv[4*c_+3]); } }

// select by literal row-in-thread index (ri)&3
#define STROW_SEL(ri, dst, par) { \
  if      (((ri) & 3) == 0) { STROW(v0, dst, par) } \
  else if (((ri) & 3) == 1) { STROW(v1, dst, par) } \
  else if (((ri) & 3) == 2) { STROW(v2, dst, par) } \
  else                      { STROW(v3, dst, par) } }

#define PIVV(KP) ( (((KP) & 3) == 0) ? v0[(KP) & 31] : \
                   (((KP) & 3) == 1) ? v1[(KP) & 31] : \
                   (((KP) & 3) == 2) ? v2[(KP) & 31] : v3[(KP) & 31] )

// one rank-2 update chunk (literal c_): 4 cols x 4 rows x 2 pivots
#define FCHUNK(c_) { \
  const float4 u4  = *(const float4*)&urA_f[(p_ << 8) + UIDX(G, c_)]; \
  const float4 uP4 = *(const float4*)&urB_f[(p_ << 8) + UIDX(G, c_)]; \
  const float w0 = uP4.x - mK1*u4.x, w1 = uP4.y - mK1*u4.y; \
  const float w2 = uP4.z - mK1*u4.z, w3 = uP4.w - mK1*u4.w; \
  v0[4*(c_)+0] = v0[4*(c_)+0] - m0*u4.x - n0*w0; \
  v0[4*(c_)+1] = v0[4*(c_)+1] - m0*u4.y - n0*w1; \
  v0[4*(c_)+2] = v0[4*(c_)+2] - m0*u4.z - n0*w2; \
  v0[4*(c_)+3] = v0[4*(c_)+3] - m0*u4.w - n0*w3; \
  v1[4*(c_)+0] = v1[4*(c_)+0] - m1*u4.x - n1*w0; \
  v1[4*(c_)+1] = v1[4*(c_)+1] - m1*u4.y - n1*w1; \
  v1[4*(c_)+2] = v1[4*(c_)+2] - m1*u4.z - n1*w2; \
  v1[4*(c_)+3] = v1[4*(c_)+3] - m1*u4.w - n1*w3; \
  v2[4*(c_)+0] = v2[4*(c_)+0] - m2*u4.x - n2*w0; \
  v2[4*(c_)+1] = v2[4*(c_)+1] - m2*u4.y - n2*w1; \
  v2[4*(c_)+2] = v2[4*(c_)+2] - m2*u4.z - n2*w2; \
  v2[4*(c_)+3] = v2[4*(c_)+3] - m2*u4.w - n2*w3; \
  v3[4*(c_)+0] = v3[4*(c_)+0] - m3*u4.x - n3*w0; \
  v3[4*(c_)+1] = v3[4*(c_)+1] - m3*u4.y - n3*w1; \
  v3[4*(c_)+2] = v3[4*(c_)+2] - m3*u4.z - n3*w2; \
  v3[4*(c_)+3] = v3[4*(c_)+3] - m3*u4.w - n3*w3; \
}

// ---- fused rank-2 elimination step: pivots K=2S and K+1, ONE barrier ----
// reads parity p=S&1 buffers; writes parity p^1 for the next fused step.
// uniform scalars go to SGPRs via rfl(); chunk loop split 4+4 with a
// sched_barrier to cap the hoisted-ds_read live range (anti-spill).
#define FSTEP(S) { \
  __syncthreads(); \
  { enum { K_ = 2*(S), p_ = (S)&1, q_ = ((S)&1)^1 }; \
  if (4*R + 3 > K_) { \
    const float uKK  = rfl(urA_f[(p_ << 8) + UIDX((K_) >> 5, ((K_) >> 2) & 7) + ((K_) & 3)]); \
    const float uK1  = rfl(urA_f[(p_ << 8) + UIDX((K_+1) >> 5, ((K_+1) >> 2) & 7) + ((K_+1) & 3)]); \
    const float uP11 = rfl(urB_f[(p_ << 8) + UIDX((K_+1) >> 5, ((K_+1) >> 2) & 7) + ((K_+1) & 3)]); \
    const float aK1K = rfl(((const float*)colA)[(p_ << 8) + (K_+1)]); \
    const float rk  = __builtin_amdgcn_rcpf(uKK); \
    const float mK1 = aK1K * rk; \
    const float u11 = uP11 - mK1 * uK1; \
    const float rk2 = __builtin_amdgcn_rcpf(u11); \
    const float4 ca = colA[p_][R], cb = colB[p_][R]; \
    const float m0 = ca.x*rk, m1 = ca.y*rk, m2 = ca.z*rk, m3 = ca.w*rk; \
    const float n0 = (cb.x - m0*uK1)*rk2, n1 = (cb.y - m1*uK1)*rk2; \
    const float n2 = (cb.z - m2*uK1)*rk2, n3 = (cb.w - m3*uK1)*rk2; \
    if (R == ((K_+2) >> 2) && G == ((K_+2) >> 5)) pivbuf[K_+1] = u11; \
    if ((G << 5) + 31 > K_ + 1) { \
      FCHUNK(0) FCHUNK(1) FCHUNK(2) FCHUNK(3) \
      __builtin_amdgcn_sched_barrier(0); \
      FCHUNK(4) FCHUNK(5) FCHUNK(6) FCHUNK(7) \
      if (R == ((K_+2) >> 2)) { STROW_SEL(K_+2, urA_f, q_) } \
      if (R == ((K_+3) >> 2)) { STROW_SEL(K_+3, urB_f, q_) } \
      if (G == ((K_+2) >> 5)) { \
        colA[q_][R] = make_float4(v0[(K_+2) & 31], v1[(K_+2) & 31], \
                                  v2[(K_+2) & 31], v3[(K_+2) & 31]); \
        colB[q_][R] = make_float4(v0[(K_+3) & 31], v1[(K_+3) & 31], \
                                  v2[(K_+3) & 31], v3[(K_+3) & 31]); \
        if (R == ((K_+2) >> 2)) pivbuf[K_+2] = PIVV(K_+2); \
      } \
    } \
  } } \
}

#define F2(S)  FSTEP(S) FSTEP((S)+1)
#define F4(S)  F2(S)  F2((S)+2)
#define F8(S)  F4(S)  F4((S)+4)
#define F16(S) F8(S)  F8((S)+8)
#define F32(S) F16(S) F16((S)+16)
#define F64(S) F32(S) F32((S)+32)

// One workgroup (512 thr) per matrix. Thread (R = t>>3, G = t&7) owns rows
// 4R..4R+3, cols 32G..32G+31, in 4 named f32x32 SSA vectors.
// Rank-2 right-looking no-pivot LU: 127 fused steps, ONE barrier each.
// Broadcasts (double-buffered, XOR-bank-swizzled rows): pivot row K (urA),
// pre-row K+1 (urB), col K (colA), pre-col K+1 (colB). Each thread
// reconstructs row K+1's update from broadcast scalars (rank-2 formula).
__global__ __launch_bounds__(512, 2) void k_lu(const int* __restrict__ x) {
  __shared__ __align__(16) float urA_f[2*NN];
  __shared__ __align__(16) float urB_f[2*NN];
  __shared__ float4 colA[2][64];
  __shared__ float4 colB[2][64];
  __shared__ float  pivbuf[NN];
  __shared__ float  rowsum[NN];
  __shared__ float  psum[8][NN];
  __shared__ int    xs[NN];
  __shared__ float  red[4];

  const int t = threadIdx.x;
  const int R = t >> 3;   // row-group: rows 4R..4R+3
  const int G = t & 7;    // col-group: cols 32G..32G+31
  // L0 (matrix BB) runs as block 0 so it isn't a lone straggler at the end
  const int m = (blockIdx.x == 0) ? BB : (blockIdx.x - 1);

  if (m < BB && t < NN) xs[t] = x[m*NN + t];
  __syncthreads();

  f32x32 v0, v1, v2, v3;
  float s0 = 0, s1 = 0, s2 = 0, s3 = 0;

  // ---- build: gather 4x32 block; accumulate per-row partial sums ----
  {
    const int r0i = (4*R + 1) & 255, r1i = (4*R + 2) & 255;
    const int r2i = (4*R + 3) & 255, r3i = (4*R + 4) & 255;
    if (m < BB) {
      const float* Tb = &g_T[0][0];
      const float* b0 = Tb + 2*xs[r0i]*(NN*NN) + r0i;
      const float* b1 = Tb + 2*xs[r1i]*(NN*NN) + r1i;
      const float* b2 = Tb + 2*xs[r2i]*(NN*NN) + r2i;
      const float* b3 = Tb + 2*xs[r3i]*(NN*NN) + r3i;
      B32(BCOLT)
    } else {
      const float* b0 = g_Ws + r0i; const float* b1 = g_Ws + r1i;
      const float* b2 = g_Ws + r2i; const float* b3 = g_Ws + r3i;
      B32(BCOLW)
    }
  }
  *(float4*)&psum[G][4*R] = make_float4(s0, s1, s2, s3);
  __syncthreads();

  // ---- per-row total: sum 8 partials + original-col-0 term ----
  if (t < NN) {
    const int r = t;
    const int ri = (r + 1) & 255;
    float tot = psum[0][r] + psum[1][r] + psum[2][r] + psum[3][r]
              + psum[4][r] + psum[5][r] + psum[6][r] + psum[7][r];
    float w0;
    if (m < BB) w0 = g_T[0][(2*xs[ri] + xs[0])*(NN*NN) + ri];
    else        w0 = g_Ws[ri];
    rowsum[r] = tot + w0;
  }
  __syncthreads();

  // ---- insert diagonal (literal element positions per R&7 arm) ----
  if (G == (R >> 3)) {
    float4 ra = *(const float4*)&rowsum[4*R];
    switch (R & 7) {
      case 0: v0[0]  = ra.x; v1[1]  = ra.y; v2[2]  = ra.z; v3[3]  = ra.w; break;
      case 1: v0[4]  = ra.x; v1[5]  = ra.y; v2[6]  = ra.z; v3[7]  = ra.w; break;
      case 2: v0[8]  = ra.x; v1[9]  = ra.y; v2[10] = ra.z; v3[11] = ra.w; break;
      case 3: v0[12] = ra.x; v1[13] = ra.y; v2[14] = ra.z; v3[15] = ra.w; break;
      case 4: v0[16] = ra.x; v1[17] = ra.y; v2[18] = ra.z; v3[19] = ra.w; break;
      case 5: v0[20] = ra.x; v1[21] = ra.y; v2[22] = ra.z; v3[23] = ra.w; break;
      case 6: v0[24] = ra.x; v1[25] = ra.y; v2[26] = ra.z; v3[27] = ra.w; break;
      default:v0[28] = ra.x; v1[29] = ra.y; v2[30] = ra.z; v3[31] = ra.w; break;
    }
  }
  // pad row 255 = e_255; its pivot is 1 (row 255 never changes: its
  // multipliers are all 0), so pivbuf[255] is preset here.
  if (R == 63) {
    v3 = (f32x32)(0.0f);
    if (G == 7) { v3[31] = 1.0f; pivbuf[255] = 1.0f; }
  }
  // initial broadcasts into parity-0 buffers: row 0, pre-row 1, col 0, pre-col 1
  if (R == 0) { STROW(v0, urA_f, 0) STROW(v1, urB_f, 0) }
  if (G == 0) {
    colA[0][R] = make_float4(v0[0], v1[0], v2[0], v3[0]);
    colB[0][R] = make_float4(v0[1], v1[1], v2[1], v3[1]);
  }
  if (t == 0) pivbuf[0] = v0[0];

  // ---- 127 fused rank-2 steps: pivots 0..253. Step 254 is a no-op
  // (only updates pad row 255, whose multipliers are 0) and pivot 255 = 1.
  F64(0) F32(64) F16(96) F8(112) F4(120) F2(124) FSTEP(126)

  // ---- log|det| = sum log|u_kk| ----
  __syncthreads();
  if (t < NN) {
    float lg = logf(fabsf(pivbuf[t]));
    #pragma unroll
    for (int off = 32; off > 0; off >>= 1) lg += __shfl_down(lg, off, 64);
    if ((t & 63) == 0) red[t >> 6] = lg;
  }
  __syncthreads();
  if (t == 0) g_ld[m] = red[0] + red[1] + red[2] + red[3];
}

__global__ void k_final(const int* __restrict__ x, float* __restrict__ out) {
  __shared__ float red[4];
  int b = blockIdx.x, t = threadIdx.x;
  int xv = x[b*NN + t];
  float lg = logf(g_V[t][xv]);
  #pragma unroll
  for (int off = 32; off > 0; off >>= 1) lg += __shfl_down(lg, off, 64);
  if ((t & 63) == 0) red[t >> 6] = lg;
  __syncthreads();
  if (t == 0) out[b] = (red[0] + red[1] + red[2] + red[3]) + g_ld[b] - g_ld[BB];
}

extern "C" void kernel_launch(void* const* d_in, const int* in_sizes, int n_in,
                              void* d_out, int out_size, void* d_ws, size_t ws_size,
                              hipStream_t stream) {
  const float* W   = (const float*)d_in[0];
  const float* lam = (const float*)d_in[1];
  const float* Vc  = (const float*)d_in[2];
  const int*   x   = (const int*)d_in[3];
  float* out = (float*)d_out;

  k_prep_v<<<dim3(1),    dim3(NN), 0, stream>>>(Vc);
  k_prep_T<<<dim3(NN),   dim3(NN), 0, stream>>>(W, lam);
  k_lu    <<<dim3(NMAT), dim3(512), 0, stream>>>(x);
  k_final <<<dim3(BB),   dim3(NN), 0, stream>>>(x, out);
}